// Round 1
// baseline (521.531 us; speedup 1.0000x reference)
//
#include <hip/hip_runtime.h>

typedef short bf16x8 __attribute__((ext_vector_type(8)));
typedef float f32x4 __attribute__((ext_vector_type(4)));

#define MASK_NEG (-1e30f)

__device__ __forceinline__ unsigned short f2bf(float f) {
  union { float f; unsigned u; } v; v.f = f;
  unsigned r = v.u + 0x7fffu + ((v.u >> 16) & 1u);
  return (unsigned short)(r >> 16);
}

__device__ __forceinline__ void gl_lds16(const void* g, void* l) {
  __builtin_amdgcn_global_load_lds(
      (__attribute__((address_space(1))) void*)(void*)g,
      (__attribute__((address_space(3))) void*)l, 16, 0, 0);
}

// -------- transpose + fp32->bf16 convert: dst[c][r] = src[r][c] --------
__global__ __launch_bounds__(256) void transpose_f32_bf16(
    const float* __restrict__ src, unsigned short* __restrict__ dst,
    int R, int C, long sstride, long dstride) {
  __shared__ float tile[64][65];
  const int z = blockIdx.z;
  const float* s = src + (size_t)z * sstride;
  unsigned short* d = dst + (size_t)z * dstride;
  const int x0 = blockIdx.x * 64;   // src col base
  const int y0 = blockIdx.y * 64;   // src row base
  const int t = threadIdx.x;
  {
    const int r = t >> 4, c4 = (t & 15) * 4;
    for (int it = 0; it < 4; ++it) {
      const int rr = r + it * 16;
      const float4 v = *(const float4*)(s + (size_t)(y0 + rr) * C + x0 + c4);
      tile[rr][c4 + 0] = v.x; tile[rr][c4 + 1] = v.y;
      tile[rr][c4 + 2] = v.z; tile[rr][c4 + 3] = v.w;
    }
  }
  __syncthreads();
  {
    const int cc = t >> 4, r4 = (t & 15) * 4;
    for (int it = 0; it < 4; ++it) {
      const int c = cc + it * 16;
      ushort4 o;
      o.x = f2bf(tile[r4 + 0][c]); o.y = f2bf(tile[r4 + 1][c]);
      o.z = f2bf(tile[r4 + 2][c]); o.w = f2bf(tile[r4 + 3][c]);
      *(ushort4*)(d + (size_t)(x0 + c) * R + y0 + r4) = o;
    }
  }
}

// -------- generic bf16 MFMA GEMM: C[M,N] = scale * A[M,K] * B[N,K]^T --------
// A, B are K-contiguous (ldA/ldB = row stride). 128x128 tile, BK=32.
// z-offsets: g = zbase + z, gb = g/zdiv, gh = g%zdiv;
//   off = z*s?l + gb*s?b + gh*s?h  (elements).
template<bool F32OUT>
__global__ __launch_bounds__(256) void gemm_tn(
    const unsigned short* __restrict__ A, const unsigned short* __restrict__ B,
    void* __restrict__ Cv,
    int K, int ldA, int ldB, int ldC, float scale,
    long sAl, long sAb, long sAh,
    long sBl, long sBb, long sBh,
    long sCl, long sCb, long sCh,
    int zbase, int zdiv)
{
  __shared__ unsigned short As[4096];  // [128 rows][32 k] bf16, chunk-swizzled
  __shared__ unsigned short Bs[4096];
  const int z = blockIdx.z;
  const int g = zbase + z;
  const int gb = g / zdiv, gh = g % zdiv;
  const unsigned short* Ab = A + (size_t)z * sAl + (size_t)gb * sAb + (size_t)gh * sAh;
  const unsigned short* Bb = B + (size_t)z * sBl + (size_t)gb * sBb + (size_t)gh * sBh;
  const int m0 = blockIdx.y * 128, n0 = blockIdx.x * 128;
  const int t = threadIdx.x;
  const int lane = t & 63;
  const int wave = t >> 6;
  const int wm = wave >> 1, wn = wave & 1;

  // staging: thread t fetches 16B chunk; row sr, slot ss, swizzled source chunk sq
  const int sr = t >> 2;
  const int ss = t & 3;
  const int sq = ss ^ (sr & 3) ^ ((sr >> 2) & 3);   // note: invariant under sr+=64

  const unsigned short* ap0 = Ab + (size_t)(m0 + sr) * ldA + sq * 8;
  const unsigned short* ap1 = Ab + (size_t)(m0 + sr + 64) * ldA + sq * 8;
  const unsigned short* bp0 = Bb + (size_t)(n0 + sr) * ldB + sq * 8;
  const unsigned short* bp1 = Bb + (size_t)(n0 + sr + 64) * ldB + sq * 8;

  char* asd0 = (char*)As + t * 16;
  char* asd1 = (char*)As + 4096 + t * 16;
  char* bsd0 = (char*)Bs + t * 16;
  char* bsd1 = (char*)Bs + 4096 + t * 16;

  // fragment read: row tq, chunk qd, swizzled LDS slot
  const int tq = lane & 15, qd = lane >> 4;
  const int slot = qd ^ (tq & 3) ^ ((tq >> 2) & 3);

  f32x4 acc[4][4];
  #pragma unroll
  for (int i = 0; i < 4; ++i)
    #pragma unroll
    for (int j = 0; j < 4; ++j)
      acc[i][j] = f32x4{0.f, 0.f, 0.f, 0.f};

  const int kIters = K >> 5;
  for (int kt = 0; kt < kIters; ++kt) {
    __syncthreads();                       // previous iter's readers done
    gl_lds16(ap0, asd0); gl_lds16(ap1, asd1);
    gl_lds16(bp0, bsd0); gl_lds16(bp1, bsd1);
    ap0 += 32; ap1 += 32; bp0 += 32; bp1 += 32;
    __builtin_amdgcn_s_waitcnt(0x0f70);    // vmcnt(0)
    __syncthreads();                       // tiles visible to all waves

    bf16x8 af[4], bfr[4];
    #pragma unroll
    for (int i = 0; i < 4; ++i)
      af[i] = *(const bf16x8*)(As + ((wm * 64 + i * 16 + tq) * 32 + slot * 8));
    #pragma unroll
    for (int j = 0; j < 4; ++j)
      bfr[j] = *(const bf16x8*)(Bs + ((wn * 64 + j * 16 + tq) * 32 + slot * 8));
    #pragma unroll
    for (int i = 0; i < 4; ++i)
      #pragma unroll
      for (int j = 0; j < 4; ++j)
        acc[i][j] = __builtin_amdgcn_mfma_f32_16x16x32_bf16(af[i], bfr[j], acc[i][j], 0, 0, 0);
  }

  const size_t cOff = (size_t)z * sCl + (size_t)gb * sCb + (size_t)gh * sCh;
  #pragma unroll
  for (int i = 0; i < 4; ++i) {
    const int row = m0 + wm * 64 + i * 16 + qd * 4;   // C/D: row=(lane>>4)*4+reg
    #pragma unroll
    for (int j = 0; j < 4; ++j) {
      const int col = n0 + wn * 64 + j * 16 + tq;     // C/D: col=lane&15
      if constexpr (F32OUT) {
        float* C = (float*)Cv + cOff;
        #pragma unroll
        for (int rr = 0; rr < 4; ++rr)
          C[(size_t)(row + rr) * ldC + col] = acc[i][j][rr] * scale;
      } else {
        unsigned short* C = (unsigned short*)Cv + cOff;
        #pragma unroll
        for (int rr = 0; rr < 4; ++rr)
          C[(size_t)(row + rr) * ldC + col] = f2bf(acc[i][j][rr] * scale);
      }
    }
  }
}

// -------- softmax over QUERY axis + transpose to attn[q][k] bf16 --------
// ST[k][q] fp32 per (b,h); mask additive along q. No max pass needed:
// |scores| <= ~21, use fixed offset exp(s-20) (identical math to softmax).
__global__ __launch_bounds__(256) void softmax_qaxis(
    const float* __restrict__ ST, unsigned short* __restrict__ P,
    const float* __restrict__ mask, int zbase)
{
  __shared__ float red[64][4];
  __shared__ float rcp[64];
  __shared__ float tile[64][65];
  const int z = blockIdx.y;
  const int g = zbase + z;
  const int b = g >> 3;
  const int k0 = blockIdx.x * 64;
  const float* S = ST + (size_t)z * 1048576 + (size_t)k0 * 1024;
  unsigned short* Pp = P + (size_t)z * 1048576;
  const float* mk = mask + (size_t)b * 1024;
  const int t = threadIdx.x;
  const int r = t >> 2, c = t & 3;

  // phase 1: per-k-row sum of exp(s + maskterm - 20) over all q
  const float4* rowp = (const float4*)(S + (size_t)r * 1024);
  const float4* mp = (const float4*)mk;
  float ssum = 0.f;
  for (int i = 0; i < 64; ++i) {
    const int idx = c + i * 4;
    const float4 v = rowp[idx];
    const float4 m4 = mp[idx];
    ssum += __expf(v.x + (1.f - m4.x) * MASK_NEG - 20.f);
    ssum += __expf(v.y + (1.f - m4.y) * MASK_NEG - 20.f);
    ssum += __expf(v.z + (1.f - m4.z) * MASK_NEG - 20.f);
    ssum += __expf(v.w + (1.f - m4.w) * MASK_NEG - 20.f);
  }
  red[r][c] = ssum;
  __syncthreads();
  if (c == 0) {
    const float Sr = red[r][0] + red[r][1] + red[r][2] + red[r][3];
    rcp[r] = 1.f / Sr;
  }

  // phase 2: 64x64 tiles: normalize + transpose-write P[q][k] bf16
  const int q_local = t >> 2, rc = t & 3;
  for (int qt = 0; qt < 16; ++qt) {
    const int qb = qt * 64;
    __syncthreads();   // also publishes rcp on first iteration
    for (int i = 0; i < 4; ++i) {
      const int cl = c * 16 + i * 4;
      const float4 v = rowp[(qb >> 2) + c * 4 + i];
      tile[r][cl + 0] = v.x; tile[r][cl + 1] = v.y;
      tile[r][cl + 2] = v.z; tile[r][cl + 3] = v.w;
    }
    __syncthreads();
    const float mq = mk[qb + q_local];
    const float addq = (1.f - mq) * MASK_NEG - 20.f;
    unsigned short* dst = Pp + (size_t)(qb + q_local) * 1024 + k0 + rc * 16;
    #pragma unroll
    for (int u = 0; u < 16; u += 2) {
      const int rr0 = rc * 16 + u;
      const float p0 = __expf(tile[rr0][q_local] + addq) * rcp[rr0];
      const float p1 = __expf(tile[rr0 + 1][q_local] + addq) * rcp[rr0 + 1];
      const unsigned pk = (unsigned)f2bf(p0) | ((unsigned)f2bf(p1) << 16);
      *(unsigned*)(dst + u) = pk;
    }
  }
}

extern "C" void kernel_launch(void* const* d_in, const int* in_sizes, int n_in,
                              void* d_out, int out_size, void* d_ws, size_t ws_size,
                              hipStream_t stream) {
  const float* x    = (const float*)d_in[0];   // [8,1024,1024]  (B,D,L)
  const float* mask = (const float*)d_in[1];   // [8,1024]
  const float* Wq   = (const float*)d_in[2];   // [8,1024,128]
  const float* Wk   = (const float*)d_in[3];
  const float* Wv   = (const float*)d_in[4];
  const float* Wo   = (const float*)d_in[5];   // [1024,1024]
  float* out = (float*)d_out;                  // [8,1024,1024]  (B,D,L)

  char* p = (char*)d_ws;
  unsigned short* xt  = (unsigned short*)p; p += 16777216;  // [b][l][d] bf16
  unsigned short* Wqt = (unsigned short*)p; p += 2097152;   // [h][dk][d]
  unsigned short* Wkt = (unsigned short*)p; p += 2097152;
  unsigned short* Wvt = (unsigned short*)p; p += 2097152;
  unsigned short* Wot = (unsigned short*)p; p += 2097152;   // [j][i]
  unsigned short* Qp  = (unsigned short*)p; p += 16777216;  // [b][h][l][dk]
  unsigned short* Kp  = (unsigned short*)p; p += 16777216;  // [b][h][l][dk]
  unsigned short* Vp  = (unsigned short*)p; p += 16777216;  // [b][h][dk][l]
  unsigned short* Hp  = (unsigned short*)p; p += 16777216;  // [b][l][h*128+dv]
  const size_t fixedBytes = (size_t)(p - (char*)d_ws);

  long nbh = 1;
  if (ws_size > fixedBytes) {
    nbh = (long)((ws_size - fixedBytes) / (4194304 + 2097152));
    if (nbh < 1) nbh = 1;
    if (nbh > 64) nbh = 64;
  }
  float* STp = (float*)p;                                        // nbh x [k][q] fp32
  unsigned short* Pp = (unsigned short*)(p + (size_t)nbh * 4194304);  // nbh x [q][k] bf16

  // prologue: transpose+convert
  transpose_f32_bf16<<<dim3(16, 16, 8), 256, 0, stream>>>(x,  xt,  1024, 1024, 1048576L, 1048576L);
  transpose_f32_bf16<<<dim3(2, 16, 8),  256, 0, stream>>>(Wq, Wqt, 1024, 128,  131072L,  131072L);
  transpose_f32_bf16<<<dim3(2, 16, 8),  256, 0, stream>>>(Wk, Wkt, 1024, 128,  131072L,  131072L);
  transpose_f32_bf16<<<dim3(2, 16, 8),  256, 0, stream>>>(Wv, Wvt, 1024, 128,  131072L,  131072L);
  transpose_f32_bf16<<<dim3(16, 16, 1), 256, 0, stream>>>(Wo, Wot, 1024, 1024, 1048576L, 1048576L);

  // Q[b,h][l][dk] = xt[b] * Wqt[h]^T    (M=1024 l, N=128 dk, K=1024 d)
  gemm_tn<false><<<dim3(1, 8, 64), 256, 0, stream>>>(
      xt, Wqt, (void*)Qp, 1024, 1024, 1024, 128, 1.f,
      0L, 1048576L, 0L,  0L, 0L, 131072L,  0L, 1048576L, 131072L, 0, 8);
  gemm_tn<false><<<dim3(1, 8, 64), 256, 0, stream>>>(
      xt, Wkt, (void*)Kp, 1024, 1024, 1024, 128, 1.f,
      0L, 1048576L, 0L,  0L, 0L, 131072L,  0L, 1048576L, 131072L, 0, 8);
  // V[b,h][dk][l] = Wvt[h] * xt[b]^T    (M=128 dk, N=1024 l, K=1024 d)
  gemm_tn<false><<<dim3(8, 1, 64), 256, 0, stream>>>(
      Wvt, xt, (void*)Vp, 1024, 1024, 1024, 1024, 1.f,
      0L, 0L, 131072L,  0L, 1048576L, 0L,  0L, 1048576L, 131072L, 0, 8);

  const float scl = 0.08838834764831845f;  // 1/sqrt(128)
  for (int s0 = 0; s0 < 64; s0 += (int)nbh) {
    const int cnt = (int)(((64 - s0) < nbh) ? (64 - s0) : nbh);
    // ST[k][q] = scale * Kp[k,:] . Qp[q,:]   (M=1024 k, N=1024 q, K=128)
    gemm_tn<true><<<dim3(8, 8, cnt), 256, 0, stream>>>(
        Kp, Qp, (void*)STp, 128, 128, 128, 1024, scl,
        0L, 1048576L, 131072L,  0L, 1048576L, 131072L,  1048576L, 0L, 0L, s0, 8);
    softmax_qaxis<<<dim3(16, cnt), 256, 0, stream>>>(STp, Pp, mask, s0);
    // H[b][q][h*128+dv] = P[q,:] . V[dv,:]   (M=1024 q, N=128 dv, K=1024 k)
    gemm_tn<false><<<dim3(1, 8, cnt), 256, 0, stream>>>(
        Pp, Vp, (void*)Hp, 1024, 1024, 1024, 1024, 1.f,
        1048576L, 0L, 0L,  0L, 1048576L, 131072L,  0L, 1048576L, 128L, s0, 8);
  }
  // out[b][j][l] = Wot[j,:] . H[b][l,:]      (M=1024 j, N=1024 l, K=1024 i)
  gemm_tn<true><<<dim3(8, 8, 8), 256, 0, stream>>>(
      Wot, Hp, (void*)out, 1024, 1024, 1024, 1024, 1.f,
      0L, 0L, 0L,  0L, 1048576L, 0L,  0L, 1048576L, 0L, 0, 1);
}

// Round 2
// 338.623 us; speedup vs baseline: 1.5401x; 1.5401x over previous
//
#include <hip/hip_runtime.h>

typedef short bf16x8 __attribute__((ext_vector_type(8)));
typedef float f32x4 __attribute__((ext_vector_type(4)));

#define MASK_NEG (-1e30f)

__device__ __forceinline__ unsigned short f2bf(float f) {
  union { float f; unsigned u; } v; v.f = f;
  unsigned r = v.u + 0x7fffu + ((v.u >> 16) & 1u);
  return (unsigned short)(r >> 16);
}

__device__ __forceinline__ float bf2f(unsigned short u) {
  union { unsigned u; float f; } v; v.u = ((unsigned)u) << 16;
  return v.f;
}

__device__ __forceinline__ void gl_lds16(const void* g, void* l) {
  __builtin_amdgcn_global_load_lds(
      (__attribute__((address_space(1))) void*)(void*)g,
      (__attribute__((address_space(3))) void*)l, 16, 0, 0);
}

// -------- transpose + fp32->bf16 convert: dst[c][r] = src[r][c] --------
__global__ __launch_bounds__(256) void transpose_f32_bf16(
    const float* __restrict__ src, unsigned short* __restrict__ dst,
    int R, int C, long sstride, long dstride) {
  __shared__ float tile[64][65];
  const int z = blockIdx.z;
  const float* s = src + (size_t)z * sstride;
  unsigned short* d = dst + (size_t)z * dstride;
  const int x0 = blockIdx.x * 64;   // src col base
  const int y0 = blockIdx.y * 64;   // src row base
  const int t = threadIdx.x;
  {
    const int r = t >> 4, c4 = (t & 15) * 4;
    for (int it = 0; it < 4; ++it) {
      const int rr = r + it * 16;
      const float4 v = *(const float4*)(s + (size_t)(y0 + rr) * C + x0 + c4);
      tile[rr][c4 + 0] = v.x; tile[rr][c4 + 1] = v.y;
      tile[rr][c4 + 2] = v.z; tile[rr][c4 + 3] = v.w;
    }
  }
  __syncthreads();
  {
    const int cc = t >> 4, r4 = (t & 15) * 4;
    for (int it = 0; it < 4; ++it) {
      const int c = cc + it * 16;
      ushort4 o;
      o.x = f2bf(tile[r4 + 0][c]); o.y = f2bf(tile[r4 + 1][c]);
      o.z = f2bf(tile[r4 + 2][c]); o.w = f2bf(tile[r4 + 3][c]);
      *(ushort4*)(d + (size_t)(x0 + c) * R + y0 + r4) = o;
    }
  }
}

// -------- generic bf16 MFMA GEMM: C[M,N] = scale * A[M,K] * B[N,K]^T --------
template<bool F32OUT>
__global__ __launch_bounds__(256) void gemm_tn(
    const unsigned short* __restrict__ A, const unsigned short* __restrict__ B,
    void* __restrict__ Cv,
    int K, int ldA, int ldB, int ldC, float scale,
    long sAl, long sAb, long sAh,
    long sBl, long sBb, long sBh,
    long sCl, long sCb, long sCh,
    int zbase, int zdiv)
{
  __shared__ unsigned short As[4096];  // [128 rows][32 k] bf16, chunk-swizzled
  __shared__ unsigned short Bs[4096];
  const int z = blockIdx.z;
  const int g = zbase + z;
  const int gb = g / zdiv, gh = g % zdiv;
  const unsigned short* Ab = A + (size_t)z * sAl + (size_t)gb * sAb + (size_t)gh * sAh;
  const unsigned short* Bb = B + (size_t)z * sBl + (size_t)gb * sBb + (size_t)gh * sBh;
  const int m0 = blockIdx.y * 128, n0 = blockIdx.x * 128;
  const int t = threadIdx.x;
  const int lane = t & 63;
  const int wave = t >> 6;
  const int wm = wave >> 1, wn = wave & 1;

  const int sr = t >> 2;
  const int ss = t & 3;
  const int sq = ss ^ (sr & 3) ^ ((sr >> 2) & 3);

  const unsigned short* ap0 = Ab + (size_t)(m0 + sr) * ldA + sq * 8;
  const unsigned short* ap1 = Ab + (size_t)(m0 + sr + 64) * ldA + sq * 8;
  const unsigned short* bp0 = Bb + (size_t)(n0 + sr) * ldB + sq * 8;
  const unsigned short* bp1 = Bb + (size_t)(n0 + sr + 64) * ldB + sq * 8;

  char* asd0 = (char*)As + t * 16;
  char* asd1 = (char*)As + 4096 + t * 16;
  char* bsd0 = (char*)Bs + t * 16;
  char* bsd1 = (char*)Bs + 4096 + t * 16;

  const int tq = lane & 15, qd = lane >> 4;
  const int slot = qd ^ (tq & 3) ^ ((tq >> 2) & 3);

  f32x4 acc[4][4];
  #pragma unroll
  for (int i = 0; i < 4; ++i)
    #pragma unroll
    for (int j = 0; j < 4; ++j)
      acc[i][j] = f32x4{0.f, 0.f, 0.f, 0.f};

  const int kIters = K >> 5;
  for (int kt = 0; kt < kIters; ++kt) {
    __syncthreads();
    gl_lds16(ap0, asd0); gl_lds16(ap1, asd1);
    gl_lds16(bp0, bsd0); gl_lds16(bp1, bsd1);
    ap0 += 32; ap1 += 32; bp0 += 32; bp1 += 32;
    __builtin_amdgcn_s_waitcnt(0x0f70);    // vmcnt(0)
    __syncthreads();

    bf16x8 af[4], bfr[4];
    #pragma unroll
    for (int i = 0; i < 4; ++i)
      af[i] = *(const bf16x8*)(As + ((wm * 64 + i * 16 + tq) * 32 + slot * 8));
    #pragma unroll
    for (int j = 0; j < 4; ++j)
      bfr[j] = *(const bf16x8*)(Bs + ((wn * 64 + j * 16 + tq) * 32 + slot * 8));
    #pragma unroll
    for (int i = 0; i < 4; ++i)
      #pragma unroll
      for (int j = 0; j < 4; ++j)
        acc[i][j] = __builtin_amdgcn_mfma_f32_16x16x32_bf16(af[i], bfr[j], acc[i][j], 0, 0, 0);
  }

  const size_t cOff = (size_t)z * sCl + (size_t)gb * sCb + (size_t)gh * sCh;
  #pragma unroll
  for (int i = 0; i < 4; ++i) {
    const int row = m0 + wm * 64 + i * 16 + qd * 4;   // C/D: row=(lane>>4)*4+reg
    #pragma unroll
    for (int j = 0; j < 4; ++j) {
      const int col = n0 + wn * 64 + j * 16 + tq;     // C/D: col=lane&15
      if constexpr (F32OUT) {
        float* C = (float*)Cv + cOff;
        #pragma unroll
        for (int rr = 0; rr < 4; ++rr)
          C[(size_t)(row + rr) * ldC + col] = acc[i][j][rr] * scale;
      } else {
        unsigned short* C = (unsigned short*)Cv + cOff;
        #pragma unroll
        for (int rr = 0; rr < 4; ++rr)
          C[(size_t)(row + rr) * ldC + col] = f2bf(acc[i][j][rr] * scale);
      }
    }
  }
}

// -------- scores GEMM with fused mask + exp + query-axis column sums --------
// E[q][k] = exp(scale*Q[q,:].K[k,:] + (1-mask[b,q])*NEG - 20), bf16, per bh.
// colsum[bh][k] += sum_q E (fp32 atomics). K=128, M=N=1024, tile 128x128.
__global__ __launch_bounds__(256) void gemm_scores_fused(
    const unsigned short* __restrict__ Q, const unsigned short* __restrict__ Km,
    unsigned short* __restrict__ E, float* __restrict__ colsum,
    const float* __restrict__ mask, int zbase)
{
  __shared__ unsigned short As[4096];
  __shared__ unsigned short Bs[4096];
  const int z = blockIdx.z;
  const int g = zbase + z;
  const int b = g >> 3;
  const unsigned short* Ab = Q + (size_t)g * 131072;
  const unsigned short* Bb = Km + (size_t)g * 131072;
  const int m0 = blockIdx.y * 128, n0 = blockIdx.x * 128;
  const int t = threadIdx.x;
  const int lane = t & 63;
  const int wave = t >> 6;
  const int wm = wave >> 1, wn = wave & 1;

  const int sr = t >> 2;
  const int ss = t & 3;
  const int sq = ss ^ (sr & 3) ^ ((sr >> 2) & 3);

  const unsigned short* ap0 = Ab + (size_t)(m0 + sr) * 128 + sq * 8;
  const unsigned short* ap1 = Ab + (size_t)(m0 + sr + 64) * 128 + sq * 8;
  const unsigned short* bp0 = Bb + (size_t)(n0 + sr) * 128 + sq * 8;
  const unsigned short* bp1 = Bb + (size_t)(n0 + sr + 64) * 128 + sq * 8;

  char* asd0 = (char*)As + t * 16;
  char* asd1 = (char*)As + 4096 + t * 16;
  char* bsd0 = (char*)Bs + t * 16;
  char* bsd1 = (char*)Bs + 4096 + t * 16;

  const int tq = lane & 15, qd = lane >> 4;
  const int slot = qd ^ (tq & 3) ^ ((tq >> 2) & 3);

  f32x4 acc[4][4];
  #pragma unroll
  for (int i = 0; i < 4; ++i)
    #pragma unroll
    for (int j = 0; j < 4; ++j)
      acc[i][j] = f32x4{0.f, 0.f, 0.f, 0.f};

  #pragma unroll
  for (int kt = 0; kt < 4; ++kt) {
    __syncthreads();
    gl_lds16(ap0, asd0); gl_lds16(ap1, asd1);
    gl_lds16(bp0, bsd0); gl_lds16(bp1, bsd1);
    ap0 += 32; ap1 += 32; bp0 += 32; bp1 += 32;
    __builtin_amdgcn_s_waitcnt(0x0f70);    // vmcnt(0)
    __syncthreads();

    bf16x8 af[4], bfr[4];
    #pragma unroll
    for (int i = 0; i < 4; ++i)
      af[i] = *(const bf16x8*)(As + ((wm * 64 + i * 16 + tq) * 32 + slot * 8));
    #pragma unroll
    for (int j = 0; j < 4; ++j)
      bfr[j] = *(const bf16x8*)(Bs + ((wn * 64 + j * 16 + tq) * 32 + slot * 8));
    #pragma unroll
    for (int i = 0; i < 4; ++i)
      #pragma unroll
      for (int j = 0; j < 4; ++j)
        acc[i][j] = __builtin_amdgcn_mfma_f32_16x16x32_bf16(af[i], bfr[j], acc[i][j], 0, 0, 0);
  }

  unsigned short* Ep = E + (size_t)z * 1048576;
  float* cs = colsum + (size_t)g * 1024;
  const float scl = 0.08838834764831845f;  // 1/sqrt(128)
  const float* mrow = mask + (size_t)b * 1024;

  float cp[4] = {0.f, 0.f, 0.f, 0.f};   // per-j partial column sums
  #pragma unroll
  for (int i = 0; i < 4; ++i) {
    const int row0 = m0 + wm * 64 + i * 16 + qd * 4;   // q index base
    #pragma unroll
    for (int rr = 0; rr < 4; ++rr) {
      const float aq = (1.f - mrow[row0 + rr]) * MASK_NEG - 20.f;
      unsigned short* erow = Ep + (size_t)(row0 + rr) * 1024 + n0 + wn * 64 + tq;
      #pragma unroll
      for (int j = 0; j < 4; ++j) {
        const float e = __expf(acc[i][j][rr] * scl + aq);
        cp[j] += e;
        erow[j * 16] = f2bf(e);
      }
    }
  }
  #pragma unroll
  for (int j = 0; j < 4; ++j) {
    float v = cp[j];
    v += __shfl_xor(v, 16, 64);
    v += __shfl_xor(v, 32, 64);
    if (qd == 0)
      atomicAdd(&cs[n0 + wn * 64 + j * 16 + tq], v);
  }
}

// -------- scale V[bh][dv][k] by 1/colsum[bh][k] in place (bf16) --------
__global__ __launch_bounds__(256) void vscale(
    unsigned short* __restrict__ V, const float* __restrict__ colsum, int zbase)
{
  const int z = blockIdx.y;
  const int g = zbase + z;
  unsigned short* Vp = V + (size_t)g * 131072;
  const float* cs = colsum + (size_t)g * 1024;
  const int idx = blockIdx.x * 256 + threadIdx.x;   // 0..16383, 8 elems each
  const int k = (idx & 127) * 8;
  const int dv = idx >> 7;
  ushort4* p = (ushort4*)(Vp + (size_t)dv * 1024 + k);
  ushort4 a = p[0], bq = p[1];
  const float4 s0 = *(const float4*)(cs + k);
  const float4 s1 = *(const float4*)(cs + k + 4);
  ushort4 oa, ob;
  oa.x = f2bf(bf2f(a.x) / s0.x); oa.y = f2bf(bf2f(a.y) / s0.y);
  oa.z = f2bf(bf2f(a.z) / s0.z); oa.w = f2bf(bf2f(a.w) / s0.w);
  ob.x = f2bf(bf2f(bq.x) / s1.x); ob.y = f2bf(bf2f(bq.y) / s1.y);
  ob.z = f2bf(bf2f(bq.z) / s1.z); ob.w = f2bf(bf2f(bq.w) / s1.w);
  p[0] = oa; p[1] = ob;
}

extern "C" void kernel_launch(void* const* d_in, const int* in_sizes, int n_in,
                              void* d_out, int out_size, void* d_ws, size_t ws_size,
                              hipStream_t stream) {
  const float* x    = (const float*)d_in[0];   // [8,1024,1024]  (B,D,L)
  const float* mask = (const float*)d_in[1];   // [8,1024]
  const float* Wq   = (const float*)d_in[2];   // [8,1024,128]
  const float* Wk   = (const float*)d_in[3];
  const float* Wv   = (const float*)d_in[4];
  const float* Wo   = (const float*)d_in[5];   // [1024,1024]
  float* out = (float*)d_out;                  // [8,1024,1024]  (B,D,L)

  char* p = (char*)d_ws;
  unsigned short* xt  = (unsigned short*)p; p += 16777216;  // [b][l][d] bf16
  unsigned short* Wqt = (unsigned short*)p; p += 2097152;   // [h][dk][d]
  unsigned short* Wkt = (unsigned short*)p; p += 2097152;
  unsigned short* Wvt = (unsigned short*)p; p += 2097152;
  unsigned short* Wot = (unsigned short*)p; p += 2097152;   // [j][i]
  unsigned short* Qp  = (unsigned short*)p; p += 16777216;  // [b][h][l][dk]
  unsigned short* Kp  = (unsigned short*)p; p += 16777216;  // [b][h][l][dk]
  unsigned short* Vp  = (unsigned short*)p; p += 16777216;  // [b][h][dk][l]
  unsigned short* Hp  = (unsigned short*)p; p += 16777216;  // [b][l][h*128+dv]
  float* colsum = (float*)p; p += 262144;                   // [64][1024] fp32
  const size_t fixedBytes = (size_t)(p - (char*)d_ws);

  long nbh = 1;
  if (ws_size > fixedBytes) {
    nbh = (long)((ws_size - fixedBytes) / 2097152);
    if (nbh < 1) nbh = 1;
    if (nbh > 64) nbh = 64;
  }
  unsigned short* Ep = (unsigned short*)p;   // nbh x [q][k] bf16 (unnormalized exp)

  hipMemsetAsync(colsum, 0, 262144, stream);

  // prologue: transpose+convert
  transpose_f32_bf16<<<dim3(16, 16, 8), 256, 0, stream>>>(x,  xt,  1024, 1024, 1048576L, 1048576L);
  transpose_f32_bf16<<<dim3(2, 16, 8),  256, 0, stream>>>(Wq, Wqt, 1024, 128,  131072L,  131072L);
  transpose_f32_bf16<<<dim3(2, 16, 8),  256, 0, stream>>>(Wk, Wkt, 1024, 128,  131072L,  131072L);
  transpose_f32_bf16<<<dim3(2, 16, 8),  256, 0, stream>>>(Wv, Wvt, 1024, 128,  131072L,  131072L);
  transpose_f32_bf16<<<dim3(16, 16, 1), 256, 0, stream>>>(Wo, Wot, 1024, 1024, 1048576L, 1048576L);

  // Q[b,h][l][dk] = xt[b] * Wqt[h]^T    (M=1024 l, N=128 dk, K=1024 d)
  gemm_tn<false><<<dim3(1, 8, 64), 256, 0, stream>>>(
      xt, Wqt, (void*)Qp, 1024, 1024, 1024, 128, 1.f,
      0L, 1048576L, 0L,  0L, 0L, 131072L,  0L, 1048576L, 131072L, 0, 8);
  gemm_tn<false><<<dim3(1, 8, 64), 256, 0, stream>>>(
      xt, Wkt, (void*)Kp, 1024, 1024, 1024, 128, 1.f,
      0L, 1048576L, 0L,  0L, 0L, 131072L,  0L, 1048576L, 131072L, 0, 8);
  // V[b,h][dk][l] = Wvt[h] * xt[b]^T    (M=128 dk, N=1024 l, K=1024 d)
  gemm_tn<false><<<dim3(8, 1, 64), 256, 0, stream>>>(
      Wvt, xt, (void*)Vp, 1024, 1024, 1024, 1024, 1.f,
      0L, 0L, 131072L,  0L, 1048576L, 0L,  0L, 1048576L, 131072L, 0, 8);

  for (int s0 = 0; s0 < 64; s0 += (int)nbh) {
    const int cnt = (int)(((64 - s0) < nbh) ? (64 - s0) : nbh);
    // E[q][k] = exp(scale*Q.K^T + mask) bf16 + colsum atomics
    gemm_scores_fused<<<dim3(8, 8, cnt), 256, 0, stream>>>(
        Qp, Kp, Ep, colsum, mask, s0);
    // V[dv][k] *= 1/colsum[k]
    vscale<<<dim3(64, cnt), 256, 0, stream>>>(Vp, colsum, s0);
    // H[b][q][h*128+dv] = E[q,:] . V'[dv,:]   (M=1024 q, N=128 dv, K=1024 k)
    gemm_tn<false><<<dim3(1, 8, cnt), 256, 0, stream>>>(
        Ep, Vp, (void*)Hp, 1024, 1024, 1024, 1024, 1.f,
        1048576L, 0L, 0L,  0L, 1048576L, 131072L,  0L, 1048576L, 128L, s0, 8);
  }
  // out[b][j][l] = Wot[j,:] . H[b][l,:]      (M=1024 j, N=1024 l, K=1024 i)
  gemm_tn<true><<<dim3(8, 8, 8), 256, 0, stream>>>(
      Wot, Hp, (void*)out, 1024, 1024, 1024, 1024, 1.f,
      0L, 0L, 0L,  0L, 1048576L, 0L,  0L, 1048576L, 0L, 0, 1);
}